// Round 10
// baseline (226.182 us; speedup 1.0000x reference)
//
#include <hip/hip_runtime.h>
#include <stdint.h>

#define BB 512
#define TT 512
#define NN 64

__device__ __forceinline__ float readlane_f(float v, int lane) {
    return __int_as_float(__builtin_amdgcn_readlane(__float_as_int(v), lane));
}

// R10 = R9 with two bug fixes (R9 returned inf):
//  (1) rule #18: inline-asm s_waitcnt does NOT order plain-C consumers of
//      asm-written registers; hipcc hoisted the BLK muls above the wait.
//      Fix: __builtin_amdgcn_sched_barrier(0) immediately after the waitcnt.
//  (2) raw ds_read addresses assumed the LDS table at offset 0; correct is
//      the 32-bit cast of the shared pointer (low word = LDS byte offset).
// Structure unchanged: diagonal E table in LDS (R4 XOR-swizzle), 64x
// v_fmac_f32_dpp per step (R8-proven), 16x ds_read_b128 + 3x ds_bpermute
// pipelined to issue at step END, consumed next step after ONE waitcnt.
// Math identical to R8 (linear space, every-4th-step pow2 rescale, int kcum,
// dhw direction probe): benched absmax 0.0.

#define S2(x) #x
#define S1(x) S2(x)

#define FMAC_DPP(ACC, QB, EV, R) \
    asm volatile("v_fmac_f32_dpp %0, %1, %2 row_ror:" S1(R) " row_mask:0xf bank_mask:0xf" \
        : "+v"(ACC) : "v"(QB), "v"(EV));
#define MUL_DPP(DST, QB, EV, R) \
    asm volatile("v_mul_f32_dpp %0, %1, %2 row_ror:" S1(R) " row_mask:0xf bank_mask:0xf" \
        : "=v"(DST) : "v"(QB), "v"(EV));
#define RD1(Cv, AD) \
    asm volatile("ds_read_b128 %0, %1" : "=v"(Cv) : "v"(AD));
#define BPERM(DST, AD, SRC) \
    asm volatile("ds_bpermute_b32 %0, %1, %2" : "=v"(DST) : "v"(AD), "v"(SRC));
// waitcnt + scheduling fence: rule #18 (consumers must not hoist above)
#define WAITLG0 { asm volatile("s_waitcnt lgkmcnt(0)"); \
                  __builtin_amdgcn_sched_barrier(0); }

// block 0: initializes the 4 accumulator chains (rot 0 = plain mul)
#define BLK_FIRST(QB, C0, C1, C2, C3) \
    a0 = QB * C0.x; \
    MUL_DPP(a1, QB, C0.y, 1)  MUL_DPP(a2, QB, C0.z, 2)  MUL_DPP(a3, QB, C0.w, 3) \
    FMAC_DPP(a0, QB, C1.x, 4)  FMAC_DPP(a1, QB, C1.y, 5) \
    FMAC_DPP(a2, QB, C1.z, 6)  FMAC_DPP(a3, QB, C1.w, 7) \
    FMAC_DPP(a0, QB, C2.x, 8)  FMAC_DPP(a1, QB, C2.y, 9) \
    FMAC_DPP(a2, QB, C2.z, 10) FMAC_DPP(a3, QB, C2.w, 11) \
    FMAC_DPP(a0, QB, C3.x, 12) FMAC_DPP(a1, QB, C3.y, 13) \
    FMAC_DPP(a2, QB, C3.z, 14) FMAC_DPP(a3, QB, C3.w, 15)

#define BLK(QB, C0, C1, C2, C3) \
    a0 = fmaf(QB, C0.x, a0); \
    FMAC_DPP(a1, QB, C0.y, 1)  FMAC_DPP(a2, QB, C0.z, 2)  FMAC_DPP(a3, QB, C0.w, 3) \
    FMAC_DPP(a0, QB, C1.x, 4)  FMAC_DPP(a1, QB, C1.y, 5) \
    FMAC_DPP(a2, QB, C1.z, 6)  FMAC_DPP(a3, QB, C1.w, 7) \
    FMAC_DPP(a0, QB, C2.x, 8)  FMAC_DPP(a1, QB, C2.y, 9) \
    FMAC_DPP(a2, QB, C2.z, 10) FMAC_DPP(a3, QB, C2.w, 11) \
    FMAC_DPP(a0, QB, C3.x, 12) FMAC_DPP(a1, QB, C3.y, 13) \
    FMAC_DPP(a2, QB, C3.z, 14) FMAC_DPP(a3, QB, C3.w, 15)

// issue next-step table reads + q rotations (consumed after next WAITLG0)
#define REFILL \
    BPERM(q1, a16, q) BPERM(q2, a32, q) BPERM(q3, a48, q) \
    RD1(C00, ad0)  RD1(C01, ad1)  RD1(C02, ad2)  RD1(C03, ad3) \
    RD1(C10, ad4)  RD1(C11, ad5)  RD1(C12, ad6)  RD1(C13, ad7) \
    RD1(C20, ad8)  RD1(C21, ad9)  RD1(C22, ad10) RD1(C23, ad11) \
    RD1(C30, ad12) RD1(C31, ad13) RD1(C32, ad14) RD1(C33, ad15)

// one step; RESC is compile-time 0/1 (rescale every 4th step)
#define STEP(tc_, EM, RESC) { \
    WAITLG0 \
    float a0, a1, a2, a3; \
    BLK_FIRST(q,  C00, C01, C02, C03) \
    BLK(q1, C10, C11, C12, C13) \
    BLK(q2, C20, C21, C22, C23) \
    BLK(q3, C30, C31, C32, C33) \
    const float s = (a0 + a1) + (a2 + a3); \
    float qn; \
    if (RESC) { \
        const int sb = __float_as_int(readlane_f(s, 0)); \
        const int kb = ((sb >> 23) & 255) - 127; \
        const float sf = __int_as_float((127 - kb) << 23);  /* 2^-kb */ \
        qn = (s * (EM)) * sf; \
        if ((tc_) <= last) kcum += kb; \
    } else { \
        qn = s * (EM); \
    } \
    q = ((tc_) <= last) ? qn : q; \
    REFILL \
}

__global__ __launch_bounds__(64, 1) void crf_kernel(
    const float* __restrict__ inputs,   // B*T*N fp32
    const float* __restrict__ trans,    // N*N fp32
    const int*   __restrict__ tags,     // B*T
    const int*   __restrict__ lens,     // B
    float*       __restrict__ out)      // [0,512) ll, [512,4608) trans copy
{
    const int b = blockIdx.x;
    const int j = threadIdx.x;          // 0..63

    // pass-through output: transition_params (4096 floats over first 64 blocks)
    if (b < 64) out[BB + b * 64 + j] = trans[b * 64 + j];

    const int L    = lens[b];
    const int last = (L - 1) > 0 ? (L - 1) : 0;

    const float* inb  = inputs + (size_t)b * TT * NN;
    const int*   tagb = tags + (size_t)b * TT;

    // ---- sequence score: unary (t < L) + binary (t+1 < L), 64 lanes x 8 ----
    float sc = 0.f;
    #pragma unroll
    for (int k = 0; k < 8; ++k) {
        const int t  = k * 64 + j;
        const int tg = tagb[t];
        if (t < L) sc += inb[t * NN + tg];
        if (t + 1 < L) sc += trans[tg * NN + tagb[t + 1]];   // L<=511 => safe
    }
    #pragma unroll
    for (int x = 32; x >= 1; x >>= 1) sc += __shfl_xor(sc, x, 64);

    // ---- DPP direction probe (R8-proven): dst[j]=src[(j&48)|((j+dhw)&15)] ----
    const int pr  = __builtin_amdgcn_update_dpp(0, j, 0x121 /*row_ror:1*/,
                                                0xf, 0xf, false);
    const int r0p = __builtin_amdgcn_readlane(pr, 0);
    const int dhw = (r0p == 1) ? 1 : -1;

    // ---- diagonal E table in LDS, R4 XOR-swizzle (0 conflicts measured).
    //      slot s=4b+k of lane j holds {D[b][4k..4k+3]} at DL4[j*16+(s^jx)],
    //      D[b][r] = exp(trans[i][j]), i=(((j&48)|((j+dhw*r)&15))+16b)&63 ----
    __shared__ __align__(16) float4 DL4[NN * 16];
    const int jx = j & 15;
    #pragma unroll
    for (int bb = 0; bb < 4; ++bb) {
        #pragma unroll
        for (int k = 0; k < 4; ++k) {
            float4 v;
            #define DV(c) { const int r = 4 * k + (c); \
                const int ii = (((j & 48) | ((j + dhw * r) & 15)) + 16 * bb) & 63; \
                ((float*)&v)[c] = __expf(trans[ii * NN + j]); }
            DV(0) DV(1) DV(2) DV(3)
            #undef DV
            DL4[j * 16 + ((4 * bb + k) ^ jx)] = v;
        }
    }
    // commit stores before the raw-asm reads (single wave, no barrier)
    asm volatile("s_waitcnt lgkmcnt(0)" ::: "memory");
    __builtin_amdgcn_sched_barrier(0);

    // loop-invariant LDS byte addresses: 32-bit cast of shared pointer
    // (low word of LDS aperture address = byte offset) -- bug fix #2.
    #define ADR(S) ((uint32_t)(uintptr_t)(&DL4[j * 16 + ((S) ^ jx)]))
    const uint32_t ad0  = ADR(0),  ad1  = ADR(1),  ad2  = ADR(2),  ad3  = ADR(3);
    const uint32_t ad4  = ADR(4),  ad5  = ADR(5),  ad6  = ADR(6),  ad7  = ADR(7);
    const uint32_t ad8  = ADR(8),  ad9  = ADR(9),  ad10 = ADR(10), ad11 = ADR(11);
    const uint32_t ad12 = ADR(12), ad13 = ADR(13), ad14 = ADR(14), ad15 = ADR(15);
    #undef ADR
    const int a16 = ((j + 16) & 63) * 4;   // bpermute addr = lane*4 (not LDS)
    const int a32 = ((j + 32) & 63) * 4;
    const int a48 = ((j + 48) & 63) * 4;

    // ---- linear-space state: q = exp(alpha - m0 - kcum*ln2) ----
    const float alpha0 = inb[j];            // t = 0
    const float m0 = readlane_f(alpha0, 0);
    float q = __expf(alpha0 - m0);
    int kcum = 0;

    // pipelined operands (written by REFILL, read next step)
    float4 C00, C01, C02, C03, C10, C11, C12, C13;
    float4 C20, C21, C22, C23, C30, C31, C32, C33;
    float q1, q2, q3;

    REFILL   // prime for the first step

    // emit prefetch: 8-step halves, double-buffered; exp off-chain (R7/R8).
    float4 fA0, fA1, fB0, fB1;

#define LD(vec, comp, tt) { const int tc_ = (tt) <= last ? (tt) : last; \
                            vec.comp = inb[tc_ * NN + j]; }
#define LOAD8(v0, v1, base) \
    LD(v0, x, (base) + 0) LD(v0, y, (base) + 1) LD(v0, z, (base) + 2) LD(v0, w, (base) + 3) \
    LD(v1, x, (base) + 4) LD(v1, y, (base) + 5) LD(v1, z, (base) + 6) LD(v1, w, (base) + 7)
#define EXP8(v0, v1) \
    v0.x = __expf(v0.x); v0.y = __expf(v0.y); v0.z = __expf(v0.z); v0.w = __expf(v0.w); \
    v1.x = __expf(v1.x); v1.y = __expf(v1.y); v1.z = __expf(v1.z); v1.w = __expf(v1.w);

    LOAD8(fA0, fA1, 1)
    EXP8(fA0, fA1)

    for (int t0 = 1; t0 <= last; t0 += 16) {
        LOAD8(fB0, fB1, t0 + 8)
        STEP(t0 + 0, fA0.x, 0) STEP(t0 + 1, fA0.y, 0)
        STEP(t0 + 2, fA0.z, 0) STEP(t0 + 3, fA0.w, 1)
        STEP(t0 + 4, fA1.x, 0) STEP(t0 + 5, fA1.y, 0)
        STEP(t0 + 6, fA1.z, 0) STEP(t0 + 7, fA1.w, 1)
        EXP8(fB0, fB1)
        LOAD8(fA0, fA1, t0 + 16)
        STEP(t0 + 8,  fB0.x, 0) STEP(t0 + 9,  fB0.y, 0)
        STEP(t0 + 10, fB0.z, 0) STEP(t0 + 11, fB0.w, 1)
        STEP(t0 + 12, fB1.x, 0) STEP(t0 + 13, fB1.y, 0)
        STEP(t0 + 14, fB1.z, 0) STEP(t0 + 15, fB1.w, 1)
        EXP8(fA0, fA1)
    }
#undef EXP8
#undef LOAD8
#undef LD

    // ---- lognorm = m0 + kcum*ln2 + log(sum_j q_j) ----
    float qs = q;
    #pragma unroll
    for (int x = 32; x >= 1; x >>= 1) qs += __shfl_xor(qs, x, 64);
    if (j == 0) {
        const double C = (double)m0 + (double)kcum * 0.6931471805599453;
        out[b] = sc - (float)((double)__logf(qs) + C);
    }
}

extern "C" void kernel_launch(void* const* d_in, const int* in_sizes, int n_in,
                              void* d_out, int out_size, void* d_ws, size_t ws_size,
                              hipStream_t stream) {
    const float* inputs = (const float*)d_in[0];
    const float* trans  = (const float*)d_in[1];
    const int*   tags   = (const int*)d_in[2];
    const int*   lens   = (const int*)d_in[3];
    float*       out    = (float*)d_out;

    crf_kernel<<<dim3(BB), dim3(64), 0, stream>>>(inputs, trans, tags, lens, out);
}

// Round 11
// 211.676 us; speedup vs baseline: 1.0685x; 1.0685x over previous
//
#include <hip/hip_runtime.h>
#include <stdint.h>

#define BB 512
#define TT 512
#define NN 64

__device__ __forceinline__ float readlane_f(float v, int lane) {
    return __int_as_float(__builtin_amdgcn_readlane(__float_as_int(v), lane));
}

// R11 = R10 with REAL software pipelining (R10 issued REFILL immediately
// before the wait -> full ~190cyc LDS drain exposed serially every step;
// 121->149 regression vs R8). Now: double-buffered C regs (CA/CB, asm-forced
// VGPRs). Per step: lgkmcnt(3) [this step's reads done, 3 bperms may remain]
// -> BLK_FIRST(q) (bperm-free) hides bperm latency -> lgkmcnt(0) -> issue 16
// reads into the OTHER buffer -> 48 FMACs hide their completion -> tail ->
// 3 bperms of new q. DS ops complete in-order; loop has no flat/SMEM ops, so
// counted lgkm waits are exact. Math identical to R8/R10 (absmax 0.0).

#define S2(x) #x
#define S1(x) S2(x)

#define FMAC_DPP(ACC, QB, EV, R) \
    asm volatile("v_fmac_f32_dpp %0, %1, %2 row_ror:" S1(R) " row_mask:0xf bank_mask:0xf" \
        : "+v"(ACC) : "v"(QB), "v"(EV));
#define MUL_DPP(DST, QB, EV, R) \
    asm volatile("v_mul_f32_dpp %0, %1, %2 row_ror:" S1(R) " row_mask:0xf bank_mask:0xf" \
        : "=v"(DST) : "v"(QB), "v"(EV));
#define RD1(Cv, AD) \
    asm volatile("ds_read_b128 %0, %1" : "=v"(Cv) : "v"(AD));
#define BPERM(DST, AD, SRC) \
    asm volatile("ds_bpermute_b32 %0, %1, %2" : "=v"(DST) : "v"(AD), "v"(SRC));
// rule #18: sched_barrier(0) after every inline-asm waitcnt
#define WAIT_LGKM(N) { asm volatile("s_waitcnt lgkmcnt(" S1(N) ")"); \
                       __builtin_amdgcn_sched_barrier(0); }

// block 0: initializes the 4 accumulator chains (rot 0 = plain mul)
#define BLK_FIRST(QB, C0, C1, C2, C3) \
    a0 = QB * C0.x; \
    MUL_DPP(a1, QB, C0.y, 1)  MUL_DPP(a2, QB, C0.z, 2)  MUL_DPP(a3, QB, C0.w, 3) \
    FMAC_DPP(a0, QB, C1.x, 4)  FMAC_DPP(a1, QB, C1.y, 5) \
    FMAC_DPP(a2, QB, C1.z, 6)  FMAC_DPP(a3, QB, C1.w, 7) \
    FMAC_DPP(a0, QB, C2.x, 8)  FMAC_DPP(a1, QB, C2.y, 9) \
    FMAC_DPP(a2, QB, C2.z, 10) FMAC_DPP(a3, QB, C2.w, 11) \
    FMAC_DPP(a0, QB, C3.x, 12) FMAC_DPP(a1, QB, C3.y, 13) \
    FMAC_DPP(a2, QB, C3.z, 14) FMAC_DPP(a3, QB, C3.w, 15)

#define BLK(QB, C0, C1, C2, C3) \
    a0 = fmaf(QB, C0.x, a0); \
    FMAC_DPP(a1, QB, C0.y, 1)  FMAC_DPP(a2, QB, C0.z, 2)  FMAC_DPP(a3, QB, C0.w, 3) \
    FMAC_DPP(a0, QB, C1.x, 4)  FMAC_DPP(a1, QB, C1.y, 5) \
    FMAC_DPP(a2, QB, C1.z, 6)  FMAC_DPP(a3, QB, C1.w, 7) \
    FMAC_DPP(a0, QB, C2.x, 8)  FMAC_DPP(a1, QB, C2.y, 9) \
    FMAC_DPP(a2, QB, C2.z, 10) FMAC_DPP(a3, QB, C2.w, 11) \
    FMAC_DPP(a0, QB, C3.x, 12) FMAC_DPP(a1, QB, C3.y, 13) \
    FMAC_DPP(a2, QB, C3.z, 14) FMAC_DPP(a3, QB, C3.w, 15)

// issue 16 table reads into buffer PB (addresses loop-invariant)
#define RD16(PB) \
    RD1(PB##00, ad0)  RD1(PB##01, ad1)  RD1(PB##02, ad2)  RD1(PB##03, ad3) \
    RD1(PB##10, ad4)  RD1(PB##11, ad5)  RD1(PB##12, ad6)  RD1(PB##13, ad7) \
    RD1(PB##20, ad8)  RD1(PB##21, ad9)  RD1(PB##22, ad10) RD1(PB##23, ad11) \
    RD1(PB##30, ad12) RD1(PB##31, ad13) RD1(PB##32, ad14) RD1(PB##33, ad15)

// one step; IB = input buffer (CA/CB), OB = output buffer for next step
#define STEP_T(tc_, EM, RESC, IB, OB) { \
    WAIT_LGKM(3)   /* IB reads retired (in-order); 3 bperms may remain */ \
    float a0, a1, a2, a3; \
    BLK_FIRST(q, IB##00, IB##01, IB##02, IB##03)   /* bperm-free block */ \
    WAIT_LGKM(0)   /* q1,q2,q3 ready (latency hidden under BLK_FIRST) */ \
    RD16(OB)       /* issue next step's reads; complete under 48 FMACs */ \
    BLK(q1, IB##10, IB##11, IB##12, IB##13) \
    BLK(q2, IB##20, IB##21, IB##22, IB##23) \
    BLK(q3, IB##30, IB##31, IB##32, IB##33) \
    const float s = (a0 + a1) + (a2 + a3); \
    float qn; \
    if (RESC) { \
        const int sb = __float_as_int(readlane_f(s, 0)); \
        const int kb = ((sb >> 23) & 255) - 127; \
        const float sf = __int_as_float((127 - kb) << 23);  /* 2^-kb */ \
        qn = (s * (EM)) * sf; \
        if ((tc_) <= last) kcum += kb; \
    } else { \
        qn = s * (EM); \
    } \
    q = ((tc_) <= last) ? qn : q; \
    BPERM(q1, a16, q) BPERM(q2, a32, q) BPERM(q3, a48, q) \
}

__global__ __launch_bounds__(64, 1) void crf_kernel(
    const float* __restrict__ inputs,   // B*T*N fp32
    const float* __restrict__ trans,    // N*N fp32
    const int*   __restrict__ tags,     // B*T
    const int*   __restrict__ lens,     // B
    float*       __restrict__ out)      // [0,512) ll, [512,4608) trans copy
{
    const int b = blockIdx.x;
    const int j = threadIdx.x;          // 0..63

    // pass-through output: transition_params (4096 floats over first 64 blocks)
    if (b < 64) out[BB + b * 64 + j] = trans[b * 64 + j];

    const int L    = lens[b];
    const int last = (L - 1) > 0 ? (L - 1) : 0;

    const float* inb  = inputs + (size_t)b * TT * NN;
    const int*   tagb = tags + (size_t)b * TT;

    // ---- sequence score: unary (t < L) + binary (t+1 < L), 64 lanes x 8 ----
    float sc = 0.f;
    #pragma unroll
    for (int k = 0; k < 8; ++k) {
        const int t  = k * 64 + j;
        const int tg = tagb[t];
        if (t < L) sc += inb[t * NN + tg];
        if (t + 1 < L) sc += trans[tg * NN + tagb[t + 1]];   // L<=511 => safe
    }
    #pragma unroll
    for (int x = 32; x >= 1; x >>= 1) sc += __shfl_xor(sc, x, 64);

    // ---- DPP direction probe (R8-proven): dst[j]=src[(j&48)|((j+dhw)&15)] ----
    const int pr  = __builtin_amdgcn_update_dpp(0, j, 0x121 /*row_ror:1*/,
                                                0xf, 0xf, false);
    const int r0p = __builtin_amdgcn_readlane(pr, 0);
    const int dhw = (r0p == 1) ? 1 : -1;

    // ---- diagonal E table in LDS, R4 XOR-swizzle (0 conflicts measured).
    //      slot s=4b+k of lane j holds {D[b][4k..4k+3]} at DL4[j*16+(s^jx)],
    //      D[b][r] = exp(trans[i][j]), i=(((j&48)|((j+dhw*r)&15))+16b)&63 ----
    __shared__ __align__(16) float4 DL4[NN * 16];
    const int jx = j & 15;
    #pragma unroll
    for (int bb = 0; bb < 4; ++bb) {
        #pragma unroll
        for (int k = 0; k < 4; ++k) {
            float4 v;
            #define DV(c) { const int r = 4 * k + (c); \
                const int ii = (((j & 48) | ((j + dhw * r) & 15)) + 16 * bb) & 63; \
                ((float*)&v)[c] = __expf(trans[ii * NN + j]); }
            DV(0) DV(1) DV(2) DV(3)
            #undef DV
            DL4[j * 16 + ((4 * bb + k) ^ jx)] = v;
        }
    }
    // commit stores before the raw-asm reads (single wave, no barrier)
    asm volatile("s_waitcnt lgkmcnt(0)" ::: "memory");
    __builtin_amdgcn_sched_barrier(0);

    // loop-invariant LDS byte addresses (32-bit cast of shared pointer)
    #define ADR(S) ((uint32_t)(uintptr_t)(&DL4[j * 16 + ((S) ^ jx)]))
    const uint32_t ad0  = ADR(0),  ad1  = ADR(1),  ad2  = ADR(2),  ad3  = ADR(3);
    const uint32_t ad4  = ADR(4),  ad5  = ADR(5),  ad6  = ADR(6),  ad7  = ADR(7);
    const uint32_t ad8  = ADR(8),  ad9  = ADR(9),  ad10 = ADR(10), ad11 = ADR(11);
    const uint32_t ad12 = ADR(12), ad13 = ADR(13), ad14 = ADR(14), ad15 = ADR(15);
    #undef ADR
    const int a16 = ((j + 16) & 63) * 4;   // bpermute addr = lane*4
    const int a32 = ((j + 32) & 63) * 4;
    const int a48 = ((j + 48) & 63) * 4;

    // ---- linear-space state: q = exp(alpha - m0 - kcum*ln2) ----
    const float alpha0 = inb[j];            // t = 0
    const float m0 = readlane_f(alpha0, 0);
    float q = __expf(alpha0 - m0);
    int kcum = 0;

    // double-buffered pipelined operands (asm "=v" => true VGPRs)
    float4 CA00, CA01, CA02, CA03, CA10, CA11, CA12, CA13;
    float4 CA20, CA21, CA22, CA23, CA30, CA31, CA32, CA33;
    float4 CB00, CB01, CB02, CB03, CB10, CB11, CB12, CB13;
    float4 CB20, CB21, CB22, CB23, CB30, CB31, CB32, CB33;
    float q1, q2, q3;

    // prime: buffer A reads + rotations of initial q
    RD16(CA)
    BPERM(q1, a16, q) BPERM(q2, a32, q) BPERM(q3, a48, q)

    // emit prefetch: 8-step halves, double-buffered; exp off-chain (R7/R8).
    float4 fA0, fA1, fB0, fB1;

#define LD(vec, comp, tt) { const int tc_ = (tt) <= last ? (tt) : last; \
                            vec.comp = inb[tc_ * NN + j]; }
#define LOAD8(v0, v1, base) \
    LD(v0, x, (base) + 0) LD(v0, y, (base) + 1) LD(v0, z, (base) + 2) LD(v0, w, (base) + 3) \
    LD(v1, x, (base) + 4) LD(v1, y, (base) + 5) LD(v1, z, (base) + 6) LD(v1, w, (base) + 7)
#define EXP8(v0, v1) \
    v0.x = __expf(v0.x); v0.y = __expf(v0.y); v0.z = __expf(v0.z); v0.w = __expf(v0.w); \
    v1.x = __expf(v1.x); v1.y = __expf(v1.y); v1.z = __expf(v1.z); v1.w = __expf(v1.w);

    LOAD8(fA0, fA1, 1)
    EXP8(fA0, fA1)

    for (int t0 = 1; t0 <= last; t0 += 16) {
        LOAD8(fB0, fB1, t0 + 8)
        STEP_T(t0 + 0,  fA0.x, 0, CA, CB) STEP_T(t0 + 1,  fA0.y, 0, CB, CA)
        STEP_T(t0 + 2,  fA0.z, 0, CA, CB) STEP_T(t0 + 3,  fA0.w, 1, CB, CA)
        STEP_T(t0 + 4,  fA1.x, 0, CA, CB) STEP_T(t0 + 5,  fA1.y, 0, CB, CA)
        STEP_T(t0 + 6,  fA1.z, 0, CA, CB) STEP_T(t0 + 7,  fA1.w, 1, CB, CA)
        EXP8(fB0, fB1)
        LOAD8(fA0, fA1, t0 + 16)
        STEP_T(t0 + 8,  fB0.x, 0, CA, CB) STEP_T(t0 + 9,  fB0.y, 0, CB, CA)
        STEP_T(t0 + 10, fB0.z, 0, CA, CB) STEP_T(t0 + 11, fB0.w, 1, CB, CA)
        STEP_T(t0 + 12, fB1.x, 0, CA, CB) STEP_T(t0 + 13, fB1.y, 0, CB, CA)
        STEP_T(t0 + 14, fB1.z, 0, CA, CB) STEP_T(t0 + 15, fB1.w, 1, CB, CA)
        EXP8(fA0, fA1)
    }
#undef EXP8
#undef LOAD8
#undef LD

    // ---- lognorm = m0 + kcum*ln2 + log(sum_j q_j) ----
    float qs = q;
    #pragma unroll
    for (int x = 32; x >= 1; x >>= 1) qs += __shfl_xor(qs, x, 64);
    if (j == 0) {
        const double C = (double)m0 + (double)kcum * 0.6931471805599453;
        out[b] = sc - (float)((double)__logf(qs) + C);
    }
}

extern "C" void kernel_launch(void* const* d_in, const int* in_sizes, int n_in,
                              void* d_out, int out_size, void* d_ws, size_t ws_size,
                              hipStream_t stream) {
    const float* inputs = (const float*)d_in[0];
    const float* trans  = (const float*)d_in[1];
    const int*   tags   = (const int*)d_in[2];
    const int*   lens   = (const int*)d_in[3];
    float*       out    = (float*)d_out;

    crf_kernel<<<dim3(BB), dim3(64), 0, stream>>>(inputs, trans, tags, lens, out);
}